// Round 1
// baseline (2486.327 us; speedup 1.0000x reference)
//
#include <hip/hip_runtime.h>

// ANI AEV: radial + angular symmetry functions, scatter-summed per atom.
// out: [40000, 224] f32, cols 0..63 radial (sp*16+k), 64..223 angular (pair*16+i*4+j)

constexpr int kOutCols = 224;
constexpr int kAngBase = 64;

__device__ __constant__ int c_triu[16] = {0,1,2,3, 1,4,5,6, 2,5,7,8, 3,6,8,9};

// Pack per-angular-edge data: {sqrt(2)*dist, sqrt(2*0.5^32)*switch, species[dst], pad}
__global__ void prep_kernel(const float* __restrict__ ang_d,
                            const float* __restrict__ ang_sw,
                            const int*   __restrict__ ang_edge_dst,
                            const int*   __restrict__ species,
                            float4* __restrict__ ea, int EA)
{
    int i = blockIdx.x * blockDim.x + threadIdx.x;
    if (i >= EA) return;
    float4 v;
    v.x = 1.41421356237f * ang_d[i];      // 0.5*sqrt(ANGULAR_ETA)=sqrt(2)
    v.y = 2.1579187e-05f * ang_sw[i];     // sqrt(2*0.5^32) = 2^-15.5
    v.z = __int_as_float(species[ang_edge_dst[i]]);
    v.w = 0.0f;
    ea[i] = v;
}

__global__ void radial_kernel(const float* __restrict__ rd,
                              const float* __restrict__ rsw,
                              const int*   __restrict__ esrc,
                              const int*   __restrict__ edst,
                              const int*   __restrict__ species,
                              float* __restrict__ out, int ER)
{
    int i = blockIdx.x * blockDim.x + threadIdx.x;
    if (i >= ER) return;
    float d   = rd[i];
    float sw  = 0.25f * rsw[i];
    int   src = esrc[i];
    int   sp  = species[edst[i]];
    float* base = out + (size_t)src * kOutCols + sp * 16;
    // bins with |d - c_k| <= 1.1 (exp(-16*1.21) ~ 4e-9 beyond)
    float t = (d - 0.8f) * (1.0f / 0.275f);
    int klo = max(0, (int)ceilf(t - 4.0f));
    int khi = min(15, (int)floorf(t + 4.0f));
    for (int k = klo; k <= khi; ++k) {
        float x = d - fmaf(0.275f, (float)k, 0.8f);
        float v = sw * __expf(-16.0f * x * x);
        if (v > 1e-8f) unsafeAtomicAdd(base + k, v);
    }
}

template <bool USE_PREP>
__global__ void angular_kernel(const float* __restrict__ angles,
                               const int*   __restrict__ cat,
                               const int*   __restrict__ asrc,
                               const int*   __restrict__ adst,
                               const float4* __restrict__ ea,
                               const float* __restrict__ ang_d,
                               const float* __restrict__ ang_sw,
                               const int*   __restrict__ aed,
                               const int*   __restrict__ species,
                               float* __restrict__ out, int P)
{
    int i = blockIdx.x * blockDim.x + threadIdx.x;
    if (i >= P) return;
    float th  = angles[i];
    int  atom = cat[i];
    int  e1i  = asrc[i];
    int  e2i  = adst[i];

    float d1, d2, w1, w2;
    int sp1, sp2;
    if (USE_PREP) {
        float4 e1 = ea[e1i];
        float4 e2 = ea[e2i];
        d1 = e1.x; w1 = e1.y; sp1 = __float_as_int(e1.z);
        d2 = e2.x; w2 = e2.y; sp2 = __float_as_int(e2.z);
    } else {
        d1 = 1.41421356237f * ang_d[e1i];
        d2 = 1.41421356237f * ang_d[e2i];
        w1 = 2.1579187e-05f * ang_sw[e1i];
        w2 = 2.1579187e-05f * ang_sw[e2i];
        sp1 = species[aed[e1i]];
        sp2 = species[aed[e2i]];
    }
    float d12 = d1 + d2;
    float f1  = w1 * w2;
    int pair = c_triu[sp1 * 4 + sp2];
    float* base = out + (size_t)atom * kOutCols + kAngBase + pair * 16;

    float s, c;
    __sincosf(th, &s, &c);
    // cos(th - a_j), a_j = pi/8 + j*pi/4
    const float ca0 = 0.92387953f, sa0 = 0.38268343f;
    float cth[4];
    cth[0] = fmaf(c,  ca0, s * sa0);
    cth[1] = fmaf(c,  sa0, s * ca0);
    cth[2] = fmaf(c, -sa0, s * ca0);
    cth[3] = fmaf(c, -ca0, s * sa0);
    float fac1[4];
    #pragma unroll
    for (int j = 0; j < 4; ++j) {
        float t  = 1.0f + cth[j];
        float t2 = t * t, t4 = t2 * t2, t8 = t4 * t4, t16 = t8 * t8;
        fac1[j]  = f1 * (t16 * t16);          // f1 * (1+cos)^32
    }
    const float shiftA[4] = {-2.2627417f, -4.1719303f, -6.0811183f, -7.9903066f};
    #pragma unroll
    for (int ii = 0; ii < 4; ++ii) {
        float x  = d12 + shiftA[ii];
        float f2 = __expf(-x * x);
        if (f2 < 1e-7f) continue;
        #pragma unroll
        for (int j = 0; j < 4; ++j) {
            float v = f2 * fac1[j];
            if (v > 1e-8f) unsafeAtomicAdd(base + ii * 4 + j, v);
        }
    }
}

extern "C" void kernel_launch(void* const* d_in, const int* in_sizes, int n_in,
                              void* d_out, int out_size, void* d_ws, size_t ws_size,
                              hipStream_t stream)
{
    const int*   species = (const int*)  d_in[0];
    const float* rad_d   = (const float*)d_in[1];
    const float* rad_sw  = (const float*)d_in[2];
    const int*   esrc    = (const int*)  d_in[3];
    const int*   edst    = (const int*)  d_in[4];
    const float* ang_d   = (const float*)d_in[5];
    const float* ang_sw  = (const float*)d_in[6];
    const float* angles  = (const float*)d_in[7];
    const int*   cat     = (const int*)  d_in[8];
    const int*   asrc    = (const int*)  d_in[9];
    const int*   adst    = (const int*)  d_in[10];
    const int*   aed     = (const int*)  d_in[11];
    float* out = (float*)d_out;

    const int ER = in_sizes[1];
    const int EA = in_sizes[5];
    const int P  = in_sizes[7];

    hipMemsetAsync(d_out, 0, (size_t)out_size * sizeof(float), stream);

    const size_t need = (size_t)EA * sizeof(float4);
    const bool use_prep = (ws_size >= need);

    if (use_prep) {
        float4* ea = (float4*)d_ws;
        prep_kernel<<<(EA + 255) / 256, 256, 0, stream>>>(ang_d, ang_sw, aed, species, ea, EA);
        radial_kernel<<<(ER + 255) / 256, 256, 0, stream>>>(rad_d, rad_sw, esrc, edst, species, out, ER);
        angular_kernel<true><<<(P + 255) / 256, 256, 0, stream>>>(
            angles, cat, asrc, adst, ea, nullptr, nullptr, nullptr, nullptr, out, P);
    } else {
        radial_kernel<<<(ER + 255) / 256, 256, 0, stream>>>(rad_d, rad_sw, esrc, edst, species, out, ER);
        angular_kernel<false><<<(P + 255) / 256, 256, 0, stream>>>(
            angles, cat, asrc, adst, nullptr, ang_d, ang_sw, aed, species, out, P);
    }
}

// Round 2
// 937.612 us; speedup vs baseline: 2.6518x; 2.6518x over previous
//
#include <hip/hip_runtime.h>

// ANI AEV: radial + angular symmetry functions, per-atom sums.
// out: [N, 224] f32, cols 0..63 radial (sp*16+k), 64..223 angular (pair*16+ii*4+j)
//
// Strategy: counting-sort edges/triples by target atom, then gather with
// wave-per-atom LDS accumulation. No global float atomics in the fast path.

constexpr int kOutCols = 224;
constexpr int kAngBase = 64;

__device__ __constant__ int c_triu[16] = {0,1,2,3, 1,4,5,6, 2,5,7,8, 3,6,8,9};

// ---------------- prep: pack per-angular-edge data ----------------
// {sqrt(2)*dist, 2^-15.5*switch, species[dst], pad}
__global__ void prep_kernel(const float* __restrict__ ang_d,
                            const float* __restrict__ ang_sw,
                            const int*   __restrict__ ang_edge_dst,
                            const int*   __restrict__ species,
                            float4* __restrict__ ea, int EA)
{
    int i = blockIdx.x * blockDim.x + threadIdx.x;
    if (i >= EA) return;
    float4 v;
    v.x = 1.41421356237f * ang_d[i];      // 0.5*sqrt(ANGULAR_ETA) = sqrt(2)
    v.y = 2.1579187e-05f * ang_sw[i];     // sqrt(2*0.5^32) = 2^-15.5
    v.z = __int_as_float(species[ang_edge_dst[i]]);
    v.w = 0.0f;
    ea[i] = v;
}

// ---------------- histogram ----------------
__global__ void hist_kernel(const int* __restrict__ idx, int* __restrict__ cnt, int n)
{
    int i = blockIdx.x * blockDim.x + threadIdx.x;
    if (i < n) atomicAdd(&cnt[idx[i]], 1);
}

// ---------------- 3-phase exclusive scan ----------------
// phase 1: per-1024-chunk exclusive scan, chunk totals to partial[]
__global__ void scan_blk(const int* __restrict__ cnt, int* __restrict__ exc,
                         int* __restrict__ partial, int n)
{
    __shared__ int wsum[16];
    int i = blockIdx.x * 1024 + threadIdx.x;
    int lane = threadIdx.x & 63, w = threadIdx.x >> 6;
    int x = (i < n) ? cnt[i] : 0;
    int v = x;
    #pragma unroll
    for (int o = 1; o < 64; o <<= 1) {
        int t = __shfl_up(v, o, 64);
        if (lane >= o) v += t;
    }
    if (lane == 63) wsum[w] = v;
    __syncthreads();
    if (w == 0 && lane < 16) {
        int s = wsum[lane];
        #pragma unroll
        for (int o = 1; o < 16; o <<= 1) {
            int t = __shfl_up(s, o, 64);
            if (lane >= o) s += t;
        }
        wsum[lane] = s;
    }
    __syncthreads();
    int wbase = (w == 0) ? 0 : wsum[w - 1];
    int incl = wbase + v;
    if (i < n) exc[i] = incl - x;
    if (threadIdx.x == 1023) partial[blockIdx.x] = wsum[15];
}

// phase 2: exclusive-scan the partials (chunked 64-wide wave scan), write totals
__device__ __forceinline__ int wave_scan_exc(int* p, int n, int lane)
{
    int run = 0;
    for (int base = 0; base < n; base += 64) {
        int i = base + lane;
        int x = (i < n) ? p[i] : 0;
        int v = x;
        #pragma unroll
        for (int o = 1; o < 64; o <<= 1) {
            int t = __shfl_up(v, o, 64);
            if (lane >= o) v += t;
        }
        if (i < n) p[i] = run + v - x;
        run += __shfl(v, 63, 64);
    }
    return run;
}

__global__ void scan_partials(int* __restrict__ pA, int nA, int* __restrict__ totA,
                              int* __restrict__ pB, int nB, int* __restrict__ totB)
{
    int lane = threadIdx.x;   // blockDim = 64
    int tA = wave_scan_exc(pA, nA, lane);
    int tB = wave_scan_exc(pB, nB, lane);
    if (lane == 0) { *totA = tA; *totB = tB; }
}

// phase 3: add chunk bases; also seed the scatter cursors
__global__ void scan_add(int* __restrict__ exc, int* __restrict__ cur,
                         const int* __restrict__ partial, int n)
{
    int i = blockIdx.x * 1024 + threadIdx.x;
    if (i >= n) return;
    int v = exc[i] + partial[blockIdx.x];
    exc[i] = v;
    cur[i] = v;
}

// ---------------- scatter into sorted record arrays ----------------
__global__ void scatter_rad(const float* __restrict__ rd, const float* __restrict__ rsw,
                            const int* __restrict__ esrc, const int* __restrict__ edst,
                            const int* __restrict__ species,
                            int* __restrict__ cur, float4* __restrict__ rec, int ER)
{
    int i = blockIdx.x * blockDim.x + threadIdx.x;
    if (i >= ER) return;
    int src = esrc[i];
    int pos = atomicAdd(&cur[src], 1);
    float4 r;
    r.x = rd[i];
    r.y = 0.25f * rsw[i];
    r.z = __int_as_float(species[edst[i]]);
    r.w = 0.0f;
    rec[pos] = r;
}

__global__ void scatter_ang(const float* __restrict__ angles, const int* __restrict__ cat,
                            const int* __restrict__ asrc, const int* __restrict__ adst,
                            const float4* __restrict__ ea,
                            int* __restrict__ cur, float4* __restrict__ rec, int P)
{
    int i = blockIdx.x * blockDim.x + threadIdx.x;
    if (i >= P) return;
    float4 e1 = ea[asrc[i]];
    float4 e2 = ea[adst[i]];
    int sp1 = __float_as_int(e1.z), sp2 = __float_as_int(e2.z);
    int pair = c_triu[sp1 * 4 + sp2];
    int pos = atomicAdd(&cur[cat[i]], 1);
    float4 r;
    r.x = angles[i];
    r.y = e1.x + e2.x;                 // d12
    r.z = e1.y * e2.y;                 // f1
    r.w = __int_as_float(pair);
    rec[pos] = r;
}

// ---------------- gather: wave per atom, LDS accumulation ----------------
__global__ void gather_rad(const float4* __restrict__ rec, const int* __restrict__ off,
                           float* __restrict__ out, int N)
{
    __shared__ float acc[4][64];
    int wave = threadIdx.x >> 6, lane = threadIdx.x & 63;
    int atom = blockIdx.x * 4 + wave;
    acc[wave][lane] = 0.0f;
    __syncthreads();
    if (atom < N) {
        int a0 = off[atom], a1 = off[atom + 1];
        for (int e = a0 + lane; e < a1; e += 64) {
            float4 r = rec[e];
            float d = r.x, sw = r.y;
            int sp = __float_as_int(r.z);
            float t = (d - 0.8f) * (1.0f / 0.275f);
            int klo = max(0, (int)ceilf(t - 4.0f));
            int khi = min(15, (int)floorf(t + 4.0f));
            for (int k = klo; k <= khi; ++k) {
                float x = d - fmaf(0.275f, (float)k, 0.8f);
                float v = sw * __expf(-16.0f * x * x);
                if (v > 1e-8f) atomicAdd(&acc[wave][sp * 16 + k], v);
            }
        }
    }
    __syncthreads();
    if (atom < N) out[(size_t)atom * kOutCols + lane] = acc[wave][lane];
}

__global__ void gather_ang(const float4* __restrict__ rec, const int* __restrict__ off,
                           float* __restrict__ out, int N)
{
    __shared__ float acc[4][160];
    int wave = threadIdx.x >> 6, lane = threadIdx.x & 63;
    int atom = blockIdx.x * 4 + wave;
    for (int c = lane; c < 160; c += 64) acc[wave][c] = 0.0f;
    __syncthreads();
    if (atom < N) {
        int a0 = off[atom], a1 = off[atom + 1];
        for (int e = a0 + lane; e < a1; e += 64) {
            float4 r = rec[e];
            float th = r.x, d12 = r.y, f1 = r.z;
            int pair = __float_as_int(r.w);
            float* base = &acc[wave][pair * 16];

            float s, c;
            __sincosf(th, &s, &c);
            const float ca0 = 0.92387953f, sa0 = 0.38268343f;
            float cth[4];
            cth[0] = fmaf(c,  ca0, s * sa0);
            cth[1] = fmaf(c,  sa0, s * ca0);
            cth[2] = fmaf(c, -sa0, s * ca0);
            cth[3] = fmaf(c, -ca0, s * sa0);
            float fac1[4];
            #pragma unroll
            for (int j = 0; j < 4; ++j) {
                float t  = 1.0f + cth[j];
                float t2 = t * t, t4 = t2 * t2, t8 = t4 * t4, t16 = t8 * t8;
                fac1[j]  = f1 * (t16 * t16);          // f1 * (1+cos)^32
            }
            const float shiftA[4] = {-2.2627417f, -4.1719303f, -6.0811183f, -7.9903066f};
            #pragma unroll
            for (int ii = 0; ii < 4; ++ii) {
                float x  = d12 + shiftA[ii];
                float f2 = __expf(-x * x);
                if (f2 < 1e-7f) continue;
                #pragma unroll
                for (int j = 0; j < 4; ++j) {
                    float v = f2 * fac1[j];
                    if (v > 1e-8f) atomicAdd(base + ii * 4 + j, v);
                }
            }
        }
    }
    __syncthreads();
    if (atom < N) {
        float* orow = out + (size_t)atom * kOutCols + kAngBase;
        for (int c = lane; c < 160; c += 64) orow[c] = acc[wave][c];
    }
}

// ---------------- fallback: direct global-atomic path (round-1) ----------------
__global__ void radial_kernel(const float* __restrict__ rd, const float* __restrict__ rsw,
                              const int* __restrict__ esrc, const int* __restrict__ edst,
                              const int* __restrict__ species,
                              float* __restrict__ out, int ER)
{
    int i = blockIdx.x * blockDim.x + threadIdx.x;
    if (i >= ER) return;
    float d   = rd[i];
    float sw  = 0.25f * rsw[i];
    int   src = esrc[i];
    int   sp  = species[edst[i]];
    float* base = out + (size_t)src * kOutCols + sp * 16;
    float t = (d - 0.8f) * (1.0f / 0.275f);
    int klo = max(0, (int)ceilf(t - 4.0f));
    int khi = min(15, (int)floorf(t + 4.0f));
    for (int k = klo; k <= khi; ++k) {
        float x = d - fmaf(0.275f, (float)k, 0.8f);
        float v = sw * __expf(-16.0f * x * x);
        if (v > 1e-8f) unsafeAtomicAdd(base + k, v);
    }
}

__global__ void angular_fallback(const float* __restrict__ angles, const int* __restrict__ cat,
                                 const int* __restrict__ asrc, const int* __restrict__ adst,
                                 const float* __restrict__ ang_d, const float* __restrict__ ang_sw,
                                 const int* __restrict__ aed, const int* __restrict__ species,
                                 float* __restrict__ out, int P)
{
    int i = blockIdx.x * blockDim.x + threadIdx.x;
    if (i >= P) return;
    int e1i = asrc[i], e2i = adst[i];
    float d1 = 1.41421356237f * ang_d[e1i];
    float d2 = 1.41421356237f * ang_d[e2i];
    float w1 = 2.1579187e-05f * ang_sw[e1i];
    float w2 = 2.1579187e-05f * ang_sw[e2i];
    int sp1 = species[aed[e1i]], sp2 = species[aed[e2i]];
    float d12 = d1 + d2;
    float f1  = w1 * w2;
    int pair = c_triu[sp1 * 4 + sp2];
    float* base = out + (size_t)cat[i] * kOutCols + kAngBase + pair * 16;

    float s, c;
    __sincosf(angles[i], &s, &c);
    const float ca0 = 0.92387953f, sa0 = 0.38268343f;
    float cth[4];
    cth[0] = fmaf(c,  ca0, s * sa0);
    cth[1] = fmaf(c,  sa0, s * ca0);
    cth[2] = fmaf(c, -sa0, s * ca0);
    cth[3] = fmaf(c, -ca0, s * sa0);
    float fac1[4];
    #pragma unroll
    for (int j = 0; j < 4; ++j) {
        float t  = 1.0f + cth[j];
        float t2 = t * t, t4 = t2 * t2, t8 = t4 * t4, t16 = t8 * t8;
        fac1[j]  = f1 * (t16 * t16);
    }
    const float shiftA[4] = {-2.2627417f, -4.1719303f, -6.0811183f, -7.9903066f};
    #pragma unroll
    for (int ii = 0; ii < 4; ++ii) {
        float x  = d12 + shiftA[ii];
        float f2 = __expf(-x * x);
        if (f2 < 1e-7f) continue;
        #pragma unroll
        for (int j = 0; j < 4; ++j) {
            float v = f2 * fac1[j];
            if (v > 1e-8f) unsafeAtomicAdd(base + ii * 4 + j, v);
        }
    }
}

extern "C" void kernel_launch(void* const* d_in, const int* in_sizes, int n_in,
                              void* d_out, int out_size, void* d_ws, size_t ws_size,
                              hipStream_t stream)
{
    const int*   species = (const int*)  d_in[0];
    const float* rad_d   = (const float*)d_in[1];
    const float* rad_sw  = (const float*)d_in[2];
    const int*   esrc    = (const int*)  d_in[3];
    const int*   edst    = (const int*)  d_in[4];
    const float* ang_d   = (const float*)d_in[5];
    const float* ang_sw  = (const float*)d_in[6];
    const float* angles  = (const float*)d_in[7];
    const int*   cat     = (const int*)  d_in[8];
    const int*   asrc    = (const int*)  d_in[9];
    const int*   adst    = (const int*)  d_in[10];
    const int*   aed     = (const int*)  d_in[11];
    float* out = (float*)d_out;

    const int N  = in_sizes[0];
    const int ER = in_sizes[1];
    const int EA = in_sizes[5];
    const int P  = in_sizes[7];

    // workspace layout
    char* w = (char*)d_ws;
    size_t pos = 0;
    auto take = [&](size_t nbytes) {
        size_t cur = pos;
        pos = (pos + nbytes + 255) & ~(size_t)255;
        return cur;
    };
    size_t ea_o   = take((size_t)EA * 16);
    size_t cnt_o  = take((size_t)2 * N * 4);        // rad_cnt | ang_cnt
    size_t roff_o = take((size_t)(N + 1) * 4);
    size_t rcur_o = take((size_t)N * 4);
    size_t aoff_o = take((size_t)(N + 1) * 4);
    size_t acur_o = take((size_t)N * 4);
    size_t part_o = take((size_t)256 * 4);          // pA | pB (128 each)
    size_t rrec_o = take((size_t)ER * 16);
    size_t arec_o = take((size_t)P * 16);
    const size_t need = pos;

    const int nbA = (N + 1023) / 1024;
    const bool sorted_ok = (ws_size >= need) && (nbA <= 128);

    if (sorted_ok) {
        float4* ea      = (float4*)(w + ea_o);
        int*    rad_cnt = (int*)(w + cnt_o);
        int*    ang_cnt = rad_cnt + N;
        int*    rad_off = (int*)(w + roff_o);
        int*    rad_cur = (int*)(w + rcur_o);
        int*    ang_off = (int*)(w + aoff_o);
        int*    ang_cur = (int*)(w + acur_o);
        int*    pA      = (int*)(w + part_o);
        int*    pB      = pA + 128;
        float4* rrec    = (float4*)(w + rrec_o);
        float4* arec    = (float4*)(w + arec_o);

        hipMemsetAsync(rad_cnt, 0, (size_t)2 * N * 4, stream);
        prep_kernel<<<(EA + 255) / 256, 256, 0, stream>>>(ang_d, ang_sw, aed, species, ea, EA);
        hist_kernel<<<(ER + 255) / 256, 256, 0, stream>>>(esrc, rad_cnt, ER);
        hist_kernel<<<(P  + 255) / 256, 256, 0, stream>>>(cat,  ang_cnt, P);
        scan_blk<<<nbA, 1024, 0, stream>>>(rad_cnt, rad_off, pA, N);
        scan_blk<<<nbA, 1024, 0, stream>>>(ang_cnt, ang_off, pB, N);
        scan_partials<<<1, 64, 0, stream>>>(pA, nbA, rad_off + N, pB, nbA, ang_off + N);
        scan_add<<<nbA, 1024, 0, stream>>>(rad_off, rad_cur, pA, N);
        scan_add<<<nbA, 1024, 0, stream>>>(ang_off, ang_cur, pB, N);
        scatter_rad<<<(ER + 255) / 256, 256, 0, stream>>>(rad_d, rad_sw, esrc, edst, species,
                                                          rad_cur, rrec, ER);
        scatter_ang<<<(P + 255) / 256, 256, 0, stream>>>(angles, cat, asrc, adst, ea,
                                                         ang_cur, arec, P);
        gather_rad<<<(N + 3) / 4, 256, 0, stream>>>(rrec, rad_off, out, N);
        gather_ang<<<(N + 3) / 4, 256, 0, stream>>>(arec, ang_off, out, N);
    } else {
        hipMemsetAsync(d_out, 0, (size_t)out_size * sizeof(float), stream);
        radial_kernel<<<(ER + 255) / 256, 256, 0, stream>>>(rad_d, rad_sw, esrc, edst, species, out, ER);
        angular_fallback<<<(P + 255) / 256, 256, 0, stream>>>(angles, cat, asrc, adst,
                                                              ang_d, ang_sw, aed, species, out, P);
    }
}